// Round 4
// baseline (669.683 us; speedup 1.0000x reference)
//
#include <hip/hip_runtime.h>
#include <math.h>

#define ALPHA 0.3f
#define KN    32
#define NPB   16   // nodes per block-group
#define NPW   4    // nodes per wave

__device__ __forceinline__ float leaky_f(float x) { return x >= 0.f ? x : ALPHA * x; }

// Monotone-counter grid barrier. ctr zeroed by hipMemsetAsync before launch.
// Safe iff all blocks co-resident (guaranteed: grid<=500, 2 blocks/CU capacity).
__device__ __forceinline__ void grid_barrier(unsigned* ctr, unsigned target)
{
    __syncthreads();
    if (threadIdx.x == 0) {
        __threadfence();   // release all prior writes to device scope
        __hip_atomic_fetch_add(ctr, 1u, __ATOMIC_RELEASE, __HIP_MEMORY_SCOPE_AGENT);
        while (__hip_atomic_load(ctr, __ATOMIC_ACQUIRE, __HIP_MEMORY_SCOPE_AGENT) < target)
            __builtin_amdgcn_s_sleep(2);
        __threadfence();   // acquire: invalidate stale cached lines
    }
    __syncthreads();
}

__global__ __launch_bounds__(256, 2) void k_pinsage(
    const float* __restrict__ emb,
    const float* __restrict__ wmat,
    const int*  __restrict__ nbr,
    const float* __restrict__ Q0w, const float* __restrict__ Q0b,
    const float* __restrict__ W0w, const float* __restrict__ W0b,
    const float* __restrict__ Q1w, const float* __restrict__ Q1b,
    const float* __restrict__ W1w, const float* __restrict__ W1b,
    float* __restrict__ out,
    float* __restrict__ h0,
    float* __restrict__ h1,
    float* __restrict__ wcache,     // may be null
    unsigned* __restrict__ ctr,
    int N, int ngrp)
{
    __shared__ float sWQ[12288];        // 48 KB: phase-dependent weight staging
    __shared__ float sx[NPB * 64];      // 4 KB
    __shared__ float sa[NPB * 64];      // 4 KB
    __shared__ int   snb[NPB * KN];     // 2 KB
    __shared__ float ssw[NPB * KN];     // 2 KB

    const int tid  = threadIdx.x;
    const int wid  = tid >> 6;
    const int lane = tid & 63;
    const unsigned nb = gridDim.x;
    const float4* sx4 = (const float4*)sx;
    const float4* sa4 = (const float4*)sa;

    // ===================== P1: h0 = leaky(emb . Q0 + Q0b) =====================
    {
        const float4* s = (const float4*)Q0w; float4* d = (float4*)sWQ;
        #pragma unroll
        for (int i = 0; i < 4; ++i) d[i * 256 + tid] = s[i * 256 + tid];
    }
    __syncthreads();
    for (int g = blockIdx.x; g < ngrp; g += nb) {
        const int bs = g * NPB;
        if (bs + NPB <= N) {
            ((float4*)sx)[tid] = ((const float4*)(emb + (size_t)bs * 64))[tid];
        } else {
            #pragma unroll
            for (int j = 0; j < NPW; ++j) {
                int slot = wid * NPW + j;
                int n = bs + slot; if (n >= N) n = N - 1;
                sx[slot * 64 + lane] = emb[(size_t)n * 64 + lane];
            }
        }
        // sx rows are wave-local: no barrier needed
        const float qb = Q0b[lane];
        float acc[NPW] = {qb, qb, qb, qb};
        #pragma unroll
        for (int c4 = 0; c4 < 16; ++c4) {
            float4 xv[NPW];
            #pragma unroll
            for (int j = 0; j < NPW; ++j) xv[j] = sx4[(wid * NPW + j) * 16 + c4];
            #pragma unroll
            for (int u = 0; u < 4; ++u) {
                float qv = sWQ[(c4 * 4 + u) * 64 + lane];
                #pragma unroll
                for (int j = 0; j < NPW; ++j)
                    acc[j] = fmaf((&xv[j].x)[u], qv, acc[j]);
            }
        }
        #pragma unroll
        for (int j = 0; j < NPW; ++j) {
            int n = bs + wid * NPW + j;
            if (n < N) h0[(size_t)n * 64 + lane] = leaky_f(acc[j]);
        }
    }
    grid_barrier(ctr, nb);

    // ====== P2: agg0 (gather h0, wmat) -> out0 -> h1  (node-local chain) ======
    {
        const float4* s1 = (const float4*)W0w; float4* d1 = (float4*)sWQ;
        #pragma unroll
        for (int i = 0; i < 8; ++i) d1[i * 256 + tid] = s1[i * 256 + tid];
        const float4* s2 = (const float4*)Q1w; float4* d2 = (float4*)(sWQ + 8192);
        #pragma unroll
        for (int i = 0; i < 4; ++i) d2[i * 256 + tid] = s2[i * 256 + tid];
    }
    __syncthreads();
    for (int g = blockIdx.x; g < ngrp; g += nb) {
        const int bs = g * NPB;
        if (bs + NPB <= N) {
            ((float4*)sx)[tid] = ((const float4*)(emb + (size_t)bs * 64))[tid];
        } else {
            #pragma unroll
            for (int j = 0; j < NPW; ++j) {
                int slot = wid * NPW + j;
                int n = bs + slot; if (n >= N) n = N - 1;
                sx[slot * 64 + lane] = emb[(size_t)n * 64 + lane];
            }
        }
        // gather: 128 (node,k) entries per wave (wave-local rows of snb/ssw)
        #pragma unroll
        for (int u = 0; u < 2; ++u) {
            int e    = wid * 128 + u * 64 + lane;
            int slot = e >> 5, k = e & 31;
            int n    = bs + slot; if (n >= N) n = N - 1;
            int id   = nbr[(size_t)n * KN + k];
            float w  = wmat[(size_t)n * (size_t)N + id];
            snb[e] = id; ssw[e] = w;
            if (wcache && bs + slot < N) wcache[(size_t)(bs + slot) * KN + k] = w;
        }
        float sumw[NPW], agg[NPW];
        #pragma unroll
        for (int j = 0; j < NPW; ++j) {
            int slot = wid * NPW + j; float s = 0.f;
            #pragma unroll
            for (int k = 0; k < KN; ++k) s += ssw[slot * KN + k];
            sumw[j] = s; agg[j] = 0.f;
        }
        #pragma unroll 4
        for (int k = 0; k < KN; ++k) {
            #pragma unroll
            for (int j = 0; j < NPW; ++j) {
                int slot = wid * NPW + j;
                size_t id = (size_t)snb[slot * KN + k];
                agg[j] = fmaf(ssw[slot * KN + k], h0[id * 64 + lane], agg[j]);
            }
        }
        #pragma unroll
        for (int j = 0; j < NPW; ++j)
            sa[(wid * NPW + j) * 64 + lane] = agg[j] / (sumw[j] + 1e-6f);

        const float wb = W0b[lane];
        float acc[NPW] = {wb, wb, wb, wb};
        #pragma unroll
        for (int c4 = 0; c4 < 16; ++c4) {
            float4 xv[NPW], av[NPW];
            #pragma unroll
            for (int j = 0; j < NPW; ++j) {
                xv[j] = sx4[(wid * NPW + j) * 16 + c4];
                av[j] = sa4[(wid * NPW + j) * 16 + c4];
            }
            #pragma unroll
            for (int u = 0; u < 4; ++u) {
                int c = c4 * 4 + u;
                float w1 = sWQ[c * 64 + lane];
                float w2 = sWQ[(64 + c) * 64 + lane];
                #pragma unroll
                for (int j = 0; j < NPW; ++j) {
                    acc[j] = fmaf((&xv[j].x)[u], w1, acc[j]);
                    acc[j] = fmaf((&av[j].x)[u], w2, acc[j]);
                }
            }
        }
        float onorm[NPW];
        #pragma unroll
        for (int j = 0; j < NPW; ++j) {
            float o = leaky_f(acc[j]);
            float ss = o * o;
            #pragma unroll
            for (int off = 32; off; off >>= 1) ss += __shfl_xor(ss, off);
            o = o / (sqrtf(ss) + 1e-6f);
            onorm[j] = o;
            int n = bs + wid * NPW + j;
            if (n < N) out[(size_t)n * 64 + lane] = o;
        }
        // fused layer-1 dense (node-local): h1 = leaky(out0 . Q1 + Q1b)
        #pragma unroll
        for (int j = 0; j < NPW; ++j)
            sx[(wid * NPW + j) * 64 + lane] = onorm[j];   // wave-local reuse
        const float qb = Q1b[lane];
        float acc1[NPW] = {qb, qb, qb, qb};
        #pragma unroll
        for (int c4 = 0; c4 < 16; ++c4) {
            float4 xv[NPW];
            #pragma unroll
            for (int j = 0; j < NPW; ++j) xv[j] = sx4[(wid * NPW + j) * 16 + c4];
            #pragma unroll
            for (int u = 0; u < 4; ++u) {
                float qv = sWQ[8192 + (c4 * 4 + u) * 64 + lane];
                #pragma unroll
                for (int j = 0; j < NPW; ++j)
                    acc1[j] = fmaf((&xv[j].x)[u], qv, acc1[j]);
            }
        }
        #pragma unroll
        for (int j = 0; j < NPW; ++j) {
            int n = bs + wid * NPW + j;
            if (n < N) h1[(size_t)n * 64 + lane] = leaky_f(acc1[j]);
        }
    }
    grid_barrier(ctr, 2 * nb);

    // ============ P3: agg1 (gather h1, wcache) -> out1 (in-place) ============
    {
        const float4* s1 = (const float4*)W1w; float4* d1 = (float4*)sWQ;
        #pragma unroll
        for (int i = 0; i < 8; ++i) d1[i * 256 + tid] = s1[i * 256 + tid];
    }
    __syncthreads();
    for (int g = blockIdx.x; g < ngrp; g += nb) {
        const int bs = g * NPB;
        if (bs + NPB <= N) {
            ((float4*)sx)[tid] = ((const float4*)(out + (size_t)bs * 64))[tid];
        } else {
            #pragma unroll
            for (int j = 0; j < NPW; ++j) {
                int slot = wid * NPW + j;
                int n = bs + slot; if (n >= N) n = N - 1;
                sx[slot * 64 + lane] = out[(size_t)n * 64 + lane];
            }
        }
        #pragma unroll
        for (int u = 0; u < 2; ++u) {
            int e    = wid * 128 + u * 64 + lane;
            int slot = e >> 5, k = e & 31;
            int n    = bs + slot; if (n >= N) n = N - 1;
            int id   = nbr[(size_t)n * KN + k];
            float w  = wcache ? wcache[(size_t)n * KN + k]
                              : wmat[(size_t)n * (size_t)N + id];
            snb[e] = id; ssw[e] = w;
        }
        float sumw[NPW], agg[NPW];
        #pragma unroll
        for (int j = 0; j < NPW; ++j) {
            int slot = wid * NPW + j; float s = 0.f;
            #pragma unroll
            for (int k = 0; k < KN; ++k) s += ssw[slot * KN + k];
            sumw[j] = s; agg[j] = 0.f;
        }
        #pragma unroll 4
        for (int k = 0; k < KN; ++k) {
            #pragma unroll
            for (int j = 0; j < NPW; ++j) {
                int slot = wid * NPW + j;
                size_t id = (size_t)snb[slot * KN + k];
                agg[j] = fmaf(ssw[slot * KN + k], h1[id * 64 + lane], agg[j]);
            }
        }
        #pragma unroll
        for (int j = 0; j < NPW; ++j)
            sa[(wid * NPW + j) * 64 + lane] = agg[j] / (sumw[j] + 1e-6f);

        const float wb = W1b[lane];
        float acc[NPW] = {wb, wb, wb, wb};
        #pragma unroll
        for (int c4 = 0; c4 < 16; ++c4) {
            float4 xv[NPW], av[NPW];
            #pragma unroll
            for (int j = 0; j < NPW; ++j) {
                xv[j] = sx4[(wid * NPW + j) * 16 + c4];
                av[j] = sa4[(wid * NPW + j) * 16 + c4];
            }
            #pragma unroll
            for (int u = 0; u < 4; ++u) {
                int c = c4 * 4 + u;
                float w1 = sWQ[c * 64 + lane];
                float w2 = sWQ[(64 + c) * 64 + lane];
                #pragma unroll
                for (int j = 0; j < NPW; ++j) {
                    acc[j] = fmaf((&xv[j].x)[u], w1, acc[j]);
                    acc[j] = fmaf((&av[j].x)[u], w2, acc[j]);
                }
            }
        }
        #pragma unroll
        for (int j = 0; j < NPW; ++j) {
            float o = leaky_f(acc[j]);
            float ss = o * o;
            #pragma unroll
            for (int off = 32; off; off >>= 1) ss += __shfl_xor(ss, off);
            int n = bs + wid * NPW + j;
            if (n < N) out[(size_t)n * 64 + lane] = o / (sqrtf(ss) + 1e-6f);
        }
    }
}

extern "C" void kernel_launch(void* const* d_in, const int* in_sizes, int n_in,
                              void* d_out, int out_size, void* d_ws, size_t ws_size,
                              hipStream_t stream)
{
    const float* emb  = (const float*)d_in[0];
    const float* wmat = (const float*)d_in[1];
    const int*   nbr  = (const int*)  d_in[2];
    const float* Q0w  = (const float*)d_in[3];
    const float* Q0b  = (const float*)d_in[4];
    const float* W0w  = (const float*)d_in[5];
    const float* W0b  = (const float*)d_in[6];
    const float* Q1w  = (const float*)d_in[7];
    const float* Q1b  = (const float*)d_in[8];
    const float* W1w  = (const float*)d_in[9];
    const float* W1b  = (const float*)d_in[10];
    float* out = (float*)d_out;

    const int N    = in_sizes[2] / KN;
    const int ngrp = (N + NPB - 1) / NPB;
    int grid = ngrp < 500 ? ngrp : 500;   // co-residency: <= 2 blocks/CU * 256 CU

    // workspace layout: [ctr 1KB][h0 N*64][h1 N*64][wcache N*32]
    unsigned* ctr = (unsigned*)d_ws;
    float* h0 = (float*)((char*)d_ws + 1024);
    float* h1 = h0 + (size_t)N * 64;
    float* wc = h1 + (size_t)N * 64;
    const size_t need = 1024 + 2 * (size_t)N * 64 * sizeof(float)
                             + (size_t)N * KN * sizeof(float);
    float* wcache = (ws_size >= need) ? wc : nullptr;

    hipMemsetAsync(ctr, 0, 64, stream);
    k_pinsage<<<grid, 256, 0, stream>>>(emb, wmat, nbr,
                                        Q0w, Q0b, W0w, W0b,
                                        Q1w, Q1b, W1w, W1b,
                                        out, h0, h1, wcache, ctr, N, ngrp);
}

// Round 5
// 541.338 us; speedup vs baseline: 1.2371x; 1.2371x over previous
//
#include <hip/hip_runtime.h>
#include <math.h>

#define ALPHA 0.3f
#define KN    32
#define NPB   24   // nodes per block (= per group)
#define NPW   6    // nodes per wave

__device__ __forceinline__ float leaky_f(float x) { return x >= 0.f ? x : ALPHA * x; }

// Monotone-counter grid barrier, co-residency guaranteed by launcher sizing.
// Spin uses RELAXED agent atomics (coherent load, NO per-iteration cache
// maintenance -- the R4 pathology). Exactly one release fence before the add
// and one acquire fence after the spin.
__device__ __forceinline__ void grid_barrier(unsigned* ctr, unsigned target)
{
    __syncthreads();
    if (threadIdx.x == 0) {
        __threadfence();   // release: flush this XCD's dirty L2 lines once
        __hip_atomic_fetch_add(ctr, 1u, __ATOMIC_RELAXED, __HIP_MEMORY_SCOPE_AGENT);
        while (__hip_atomic_load(ctr, __ATOMIC_RELAXED, __HIP_MEMORY_SCOPE_AGENT) < target)
            __builtin_amdgcn_s_sleep(8);
        __threadfence();   // acquire: invalidate stale lines once
    }
    __syncthreads();
}

__global__ __launch_bounds__(256, 2) void k_pinsage(
    const float* __restrict__ emb,
    const float* __restrict__ wmat,
    const int*  __restrict__ nbr,
    const float* __restrict__ Q0w, const float* __restrict__ Q0b,
    const float* __restrict__ W0w, const float* __restrict__ W0b,
    const float* __restrict__ Q1w, const float* __restrict__ Q1b,
    const float* __restrict__ W1w, const float* __restrict__ W1b,
    float* __restrict__ out,
    float* __restrict__ h0,
    float* __restrict__ h1,
    unsigned* __restrict__ ctr,
    int N)
{
    __shared__ float sWQ[12288];       // 48 KB phase-staged weights
    __shared__ float sx[NPB * 64];     // 6 KB
    __shared__ float sa[NPB * 64];     // 6 KB
    __shared__ int   snb[NPB * KN];    // 3 KB
    __shared__ float ssw[NPB * KN];    // 3 KB   => 66 KB total, 2 blocks/CU

    const int tid  = threadIdx.x;
    const int wid  = tid >> 6;
    const int lane = tid & 63;
    const unsigned nb = gridDim.x;
    const int bs = blockIdx.x * NPB;   // one group per block (grid == ngrp)
    const float4* sx4 = (const float4*)sx;
    const float4* sa4 = (const float4*)sa;

    // ==== issue the latency-critical random gathers FIRST; results live in
    // registers across both barriers (same w/id used by both layers) ====
    int   gid[3]; float gwv[3];
    #pragma unroll
    for (int u = 0; u < 3; ++u) {
        int e = wid * 192 + u * 64 + lane;       // wave-local entries
        int n = bs + (e >> 5); if (n >= N) n = N - 1;
        gid[u] = nbr[(size_t)n * KN + (e & 31)];
    }
    #pragma unroll
    for (int u = 0; u < 3; ++u) {
        int e = wid * 192 + u * 64 + lane;
        int n = bs + (e >> 5); if (n >= N) n = N - 1;
        gwv[u] = wmat[(size_t)n * (size_t)N + gid[u]];
    }

    // ===================== P1: h0 = leaky(emb . Q0 + b) =====================
    {
        const float4* s = (const float4*)Q0w; float4* d = (float4*)sWQ;
        #pragma unroll
        for (int i = 0; i < 4; ++i) d[i * 256 + tid] = s[i * 256 + tid];
    }
    #pragma unroll
    for (int u = 0; u < 2; ++u) {                 // stage 24 emb rows (wave-local)
        int idx = u * 64 + lane;
        if (idx < 96) {
            int f4 = wid * 96 + idx;
            int n  = bs + (f4 >> 4); if (n >= N) n = N - 1;
            ((float4*)sx)[f4] = ((const float4*)emb)[(size_t)n * 16 + (f4 & 15)];
        }
    }
    __syncthreads();

    {
        const float qb = Q0b[lane];
        float acc[NPW];
        #pragma unroll
        for (int j = 0; j < NPW; ++j) acc[j] = qb;
        #pragma unroll
        for (int c4 = 0; c4 < 16; ++c4) {
            float4 xv[NPW];
            #pragma unroll
            for (int j = 0; j < NPW; ++j) xv[j] = sx4[(wid * NPW + j) * 16 + c4];
            #pragma unroll
            for (int u = 0; u < 4; ++u) {
                float qv = sWQ[(c4 * 4 + u) * 64 + lane];
                #pragma unroll
                for (int j = 0; j < NPW; ++j)
                    acc[j] = fmaf((&xv[j].x)[u], qv, acc[j]);
            }
        }
        #pragma unroll
        for (int j = 0; j < NPW; ++j) {
            int n = bs + wid * NPW + j;
            if (n < N) h0[(size_t)n * 64 + lane] = leaky_f(acc[j]);
        }
    }
    grid_barrier(ctr, nb);

    // ====== P2: agg0(h0) -> out0 -> h1 (fused node-local layer-1 dense) ======
    {
        const float4* s1 = (const float4*)W0w; float4* d1 = (float4*)sWQ;
        #pragma unroll
        for (int i = 0; i < 8; ++i) d1[i * 256 + tid] = s1[i * 256 + tid];
        const float4* s2 = (const float4*)Q1w; float4* d2 = (float4*)(sWQ + 8192);
        #pragma unroll
        for (int i = 0; i < 4; ++i) d2[i * 256 + tid] = s2[i * 256 + tid];
    }
    #pragma unroll
    for (int u = 0; u < 3; ++u) {                 // dump reg stash (wave-local)
        int e = wid * 192 + u * 64 + lane;
        snb[e] = gid[u]; ssw[e] = gwv[u];
    }
    #pragma unroll
    for (int u = 0; u < 2; ++u) {
        int idx = u * 64 + lane;
        if (idx < 96) {
            int f4 = wid * 96 + idx;
            int n  = bs + (f4 >> 4); if (n >= N) n = N - 1;
            ((float4*)sx)[f4] = ((const float4*)emb)[(size_t)n * 16 + (f4 & 15)];
        }
    }
    __syncthreads();

    {
        float sumw[NPW], agg[NPW];
        #pragma unroll
        for (int j = 0; j < NPW; ++j) {
            int slot = wid * NPW + j; float s = 0.f;
            #pragma unroll
            for (int k = 0; k < KN; ++k) s += ssw[slot * KN + k];
            sumw[j] = s; agg[j] = 0.f;
        }
        #pragma unroll 4
        for (int k = 0; k < KN; ++k) {
            #pragma unroll
            for (int j = 0; j < NPW; ++j) {
                int slot = wid * NPW + j;
                size_t id = (size_t)snb[slot * KN + k];
                agg[j] = fmaf(ssw[slot * KN + k], h0[id * 64 + lane], agg[j]);
            }
        }
        #pragma unroll
        for (int j = 0; j < NPW; ++j)
            sa[(wid * NPW + j) * 64 + lane] = agg[j] / (sumw[j] + 1e-6f);

        const float wb = W0b[lane];
        float acc[NPW];
        #pragma unroll
        for (int j = 0; j < NPW; ++j) acc[j] = wb;
        #pragma unroll
        for (int c4 = 0; c4 < 16; ++c4) {
            float4 xv[NPW], av[NPW];
            #pragma unroll
            for (int j = 0; j < NPW; ++j) {
                xv[j] = sx4[(wid * NPW + j) * 16 + c4];
                av[j] = sa4[(wid * NPW + j) * 16 + c4];
            }
            #pragma unroll
            for (int u = 0; u < 4; ++u) {
                int c = c4 * 4 + u;
                float w1 = sWQ[c * 64 + lane];
                float w2 = sWQ[(64 + c) * 64 + lane];
                #pragma unroll
                for (int j = 0; j < NPW; ++j) {
                    acc[j] = fmaf((&xv[j].x)[u], w1, acc[j]);
                    acc[j] = fmaf((&av[j].x)[u], w2, acc[j]);
                }
            }
        }
        float onorm[NPW];
        #pragma unroll
        for (int j = 0; j < NPW; ++j) {
            float o = leaky_f(acc[j]);
            float ss = o * o;
            #pragma unroll
            for (int off = 32; off; off >>= 1) ss += __shfl_xor(ss, off);
            o = o / (sqrtf(ss) + 1e-6f);
            onorm[j] = o;
            int n = bs + wid * NPW + j;
            if (n < N) out[(size_t)n * 64 + lane] = o;
        }
        // fused layer-1 dense: h1 = leaky(out0 . Q1 + b)   (node-local)
        #pragma unroll
        for (int j = 0; j < NPW; ++j)
            sx[(wid * NPW + j) * 64 + lane] = onorm[j];    // wave-local reuse
        const float qb = Q1b[lane];
        float acc1[NPW];
        #pragma unroll
        for (int j = 0; j < NPW; ++j) acc1[j] = qb;
        #pragma unroll
        for (int c4 = 0; c4 < 16; ++c4) {
            float4 xv[NPW];
            #pragma unroll
            for (int j = 0; j < NPW; ++j) xv[j] = sx4[(wid * NPW + j) * 16 + c4];
            #pragma unroll
            for (int u = 0; u < 4; ++u) {
                float qv = sWQ[8192 + (c4 * 4 + u) * 64 + lane];
                #pragma unroll
                for (int j = 0; j < NPW; ++j)
                    acc1[j] = fmaf((&xv[j].x)[u], qv, acc1[j]);
            }
        }
        #pragma unroll
        for (int j = 0; j < NPW; ++j) {
            int n = bs + wid * NPW + j;
            if (n < N) h1[(size_t)n * 64 + lane] = leaky_f(acc1[j]);
        }
    }
    grid_barrier(ctr, 2 * nb);

    // ============ P3: agg1(h1) -> out1 (in-place on out) ============
    {
        const float4* s1 = (const float4*)W1w; float4* d1 = (float4*)sWQ;
        #pragma unroll
        for (int i = 0; i < 8; ++i) d1[i * 256 + tid] = s1[i * 256 + tid];
    }
    #pragma unroll
    for (int u = 0; u < 2; ++u) {                 // stage own out0 rows
        int idx = u * 64 + lane;
        if (idx < 96) {
            int f4 = wid * 96 + idx;
            int n  = bs + (f4 >> 4); if (n >= N) n = N - 1;
            ((float4*)sx)[f4] = ((const float4*)out)[(size_t)n * 16 + (f4 & 15)];
        }
    }
    __syncthreads();

    {
        float sumw[NPW], agg[NPW];
        #pragma unroll
        for (int j = 0; j < NPW; ++j) {
            int slot = wid * NPW + j; float s = 0.f;
            #pragma unroll
            for (int k = 0; k < KN; ++k) s += ssw[slot * KN + k];
            sumw[j] = s; agg[j] = 0.f;
        }
        #pragma unroll 4
        for (int k = 0; k < KN; ++k) {
            #pragma unroll
            for (int j = 0; j < NPW; ++j) {
                int slot = wid * NPW + j;
                size_t id = (size_t)snb[slot * KN + k];
                agg[j] = fmaf(ssw[slot * KN + k], h1[id * 64 + lane], agg[j]);
            }
        }
        #pragma unroll
        for (int j = 0; j < NPW; ++j)
            sa[(wid * NPW + j) * 64 + lane] = agg[j] / (sumw[j] + 1e-6f);

        const float wb = W1b[lane];
        float acc[NPW];
        #pragma unroll
        for (int j = 0; j < NPW; ++j) acc[j] = wb;
        #pragma unroll
        for (int c4 = 0; c4 < 16; ++c4) {
            float4 xv[NPW], av[NPW];
            #pragma unroll
            for (int j = 0; j < NPW; ++j) {
                xv[j] = sx4[(wid * NPW + j) * 16 + c4];
                av[j] = sa4[(wid * NPW + j) * 16 + c4];
            }
            #pragma unroll
            for (int u = 0; u < 4; ++u) {
                int c = c4 * 4 + u;
                float w1 = sWQ[c * 64 + lane];
                float w2 = sWQ[(64 + c) * 64 + lane];
                #pragma unroll
                for (int j = 0; j < NPW; ++j) {
                    acc[j] = fmaf((&xv[j].x)[u], w1, acc[j]);
                    acc[j] = fmaf((&av[j].x)[u], w2, acc[j]);
                }
            }
        }
        #pragma unroll
        for (int j = 0; j < NPW; ++j) {
            float o = leaky_f(acc[j]);
            float ss = o * o;
            #pragma unroll
            for (int off = 32; off; off >>= 1) ss += __shfl_xor(ss, off);
            int n = bs + wid * NPW + j;
            if (n < N) out[(size_t)n * 64 + lane] = o / (sqrtf(ss) + 1e-6f);
        }
    }
}

extern "C" void kernel_launch(void* const* d_in, const int* in_sizes, int n_in,
                              void* d_out, int out_size, void* d_ws, size_t ws_size,
                              hipStream_t stream)
{
    const float* emb  = (const float*)d_in[0];
    const float* wmat = (const float*)d_in[1];
    const int*   nbr  = (const int*)  d_in[2];
    const float* Q0w  = (const float*)d_in[3];
    const float* Q0b  = (const float*)d_in[4];
    const float* W0w  = (const float*)d_in[5];
    const float* W0b  = (const float*)d_in[6];
    const float* Q1w  = (const float*)d_in[7];
    const float* Q1b  = (const float*)d_in[8];
    const float* W1w  = (const float*)d_in[9];
    const float* W1b  = (const float*)d_in[10];
    float* out = (float*)d_out;

    const int N    = in_sizes[2] / KN;           // 12000
    const int grid = (N + NPB - 1) / NPB;        // 500 (<=512: co-resident @2/CU)

    unsigned* ctr = (unsigned*)d_ws;
    float* h0 = (float*)((char*)d_ws + 256);
    float* h1 = h0 + (size_t)N * 64;

    hipMemsetAsync(ctr, 0, 256, stream);
    k_pinsage<<<grid, 256, 0, stream>>>(emb, wmat, nbr,
                                        Q0w, Q0b, W0w, W0b,
                                        Q1w, Q1b, W1w, W1b,
                                        out, h0, h1, ctr, N);
}

// Round 6
// 227.406 us; speedup vs baseline: 2.9449x; 2.3805x over previous
//
#include <hip/hip_runtime.h>
#include <math.h>

#define ALPHA 0.3f
#define KN    32

__device__ __forceinline__ float leaky_f(float x) { return x >= 0.f ? x : ALPHA * x; }

// ---------------------------------------------------------------------------
// K1: h0[n,h] = leaky( sum_c emb[n,c]*Q0w[c,h] + Q0b[h] )
// NPB=16 nodes/block, 4 waves x 4 nodes, 20 KB LDS.
// ---------------------------------------------------------------------------
__global__ __launch_bounds__(256) void k_dense(const float* __restrict__ X,
                                               const float* __restrict__ Qw,
                                               const float* __restrict__ Qb,
                                               float* __restrict__ Hout, int N)
{
    __shared__ float sQ[64 * 64];
    __shared__ float sX[16 * 64];
    const int tid  = threadIdx.x;
    const int wid  = tid >> 6;
    const int lane = tid & 63;
    const int bs   = blockIdx.x * 16;

    {
        const float4* s = (const float4*)Qw; float4* d = (float4*)sQ;
        #pragma unroll
        for (int i = 0; i < 4; ++i) d[i * 256 + tid] = s[i * 256 + tid];
    }
    // wave-local row staging (each wave stages its own 4 rows)
    #pragma unroll
    for (int j = 0; j < 4; ++j) {
        int slot = wid * 4 + j;
        int n = bs + slot; if (n >= N) n = N - 1;
        if (lane < 16)
            ((float4*)sX)[slot * 16 + lane] = ((const float4*)X)[(size_t)n * 16 + lane];
    }
    __syncthreads();

    const float qb = Qb[lane];
    float acc[4] = {qb, qb, qb, qb};
    const float4* sX4 = (const float4*)sX;
    #pragma unroll
    for (int c4 = 0; c4 < 16; ++c4) {
        float4 xv[4];
        #pragma unroll
        for (int j = 0; j < 4; ++j) xv[j] = sX4[(wid * 4 + j) * 16 + c4];
        #pragma unroll
        for (int u = 0; u < 4; ++u) {
            float qv = sQ[(c4 * 4 + u) * 64 + lane];
            #pragma unroll
            for (int j = 0; j < 4; ++j)
                acc[j] = fmaf((&xv[j].x)[u], qv, acc[j]);
        }
    }
    #pragma unroll
    for (int j = 0; j < 4; ++j) {
        int n = bs + wid * 4 + j;
        if (n < N) Hout[(size_t)n * 64 + lane] = leaky_f(acc[j]);
    }
}

// ---------------------------------------------------------------------------
// K2: per node n: w=wmat[n,nbr], agg=Σw·h0[nbr]/Σw, out0=norm(leaky([x,agg]·W0)),
//     h1=leaky(out0·Q1)  [Q1w re-staged into sW after combine — LDS stays 38 KB]
// NPB=8 (4 waves x 2 nodes), grid=1500, 4 blocks/CU.
// ---------------------------------------------------------------------------
__global__ __launch_bounds__(256, 4) void k_conv_fused(
    const float* __restrict__ X,
    const float* __restrict__ Hbuf,
    const float* __restrict__ Wmat,
    const int*  __restrict__ nbr,
    float* __restrict__ wcache,
    const float* __restrict__ Ww,    // 128x64
    const float* __restrict__ Wb,
    const float* __restrict__ Qw,    // 64x64
    const float* __restrict__ Qb,
    float* __restrict__ OUT,
    float* __restrict__ H1out,
    int N)
{
    __shared__ float sW[128 * 64];   // 32 KB (W0w, then reused for Q1w)
    __shared__ float sx[8 * 64];     // 2 KB
    __shared__ float sa[8 * 64];     // 2 KB
    __shared__ int   snb[8 * KN];    // 1 KB
    __shared__ float ssw[8 * KN];    // 1 KB    => 38 KB, 4 blocks/CU

    const int tid  = threadIdx.x;
    const int wid  = tid >> 6;
    const int lane = tid & 63;
    const int bs   = blockIdx.x * 8;

    // --- issue random gathers FIRST (one (node,k) entry per thread) ---
    const int e    = tid;                 // == wid*64 + lane (wave-local range)
    const int slot = e >> 5;
    int ng = bs + slot; if (ng >= N) ng = N - 1;
    const int   id = nbr[(size_t)ng * KN + (e & 31)];
    const float w  = Wmat[(size_t)ng * (size_t)N + id];

    // --- stage W0w while gathers are in flight ---
    {
        const float4* s = (const float4*)Ww; float4* d = (float4*)sW;
        #pragma unroll
        for (int i = 0; i < 8; ++i) d[i * 256 + tid] = s[i * 256 + tid];
    }
    // wave-local staging: own 2 rows of X, own 64 gather entries
    #pragma unroll
    for (int j = 0; j < 2; ++j) {
        int sl = wid * 2 + j;
        int n = bs + sl; if (n >= N) n = N - 1;
        if (lane < 16)
            ((float4*)sx)[sl * 16 + lane] = ((const float4*)X)[(size_t)n * 16 + lane];
    }
    snb[e] = id;
    ssw[e] = w;
    if (wcache && bs + slot < N)
        wcache[(size_t)bs * KN + e] = w;   // coalesced: one float per thread

    // --- neighbor aggregation (wave-local LDS, no block barrier needed) ---
    float sumw[2], ag0[2], ag1[2];
    #pragma unroll
    for (int j = 0; j < 2; ++j) {
        float s = 0.f;
        #pragma unroll
        for (int k = 0; k < KN; ++k) s += ssw[wid * 64 + j * 32 + k];
        sumw[j] = s; ag0[j] = 0.f; ag1[j] = 0.f;
    }
    #pragma unroll 8
    for (int k = 0; k < KN; k += 2) {
        #pragma unroll
        for (int j = 0; j < 2; ++j) {
            size_t i0 = (size_t)snb[wid * 64 + j * 32 + k];
            size_t i1 = (size_t)snb[wid * 64 + j * 32 + k + 1];
            ag0[j] = fmaf(ssw[wid * 64 + j * 32 + k],     Hbuf[i0 * 64 + lane], ag0[j]);
            ag1[j] = fmaf(ssw[wid * 64 + j * 32 + k + 1], Hbuf[i1 * 64 + lane], ag1[j]);
        }
    }
    #pragma unroll
    for (int j = 0; j < 2; ++j)
        sa[(wid * 2 + j) * 64 + lane] = (ag0[j] + ag1[j]) / (sumw[j] + 1e-6f);
    __syncthreads();   // sW staged (and all LDS visible)

    // --- combine GEMV: [x|agg] . W0 + b ---
    const float4* sx4 = (const float4*)sx;
    const float4* sa4 = (const float4*)sa;
    const float wb = Wb[lane];
    float acc[2] = {wb, wb};
    #pragma unroll
    for (int c4 = 0; c4 < 16; ++c4) {
        float4 xv[2], av[2];
        #pragma unroll
        for (int j = 0; j < 2; ++j) {
            xv[j] = sx4[(wid * 2 + j) * 16 + c4];
            av[j] = sa4[(wid * 2 + j) * 16 + c4];
        }
        #pragma unroll
        for (int u = 0; u < 4; ++u) {
            int c = c4 * 4 + u;
            float w1 = sW[c * 64 + lane];
            float w2 = sW[(64 + c) * 64 + lane];
            #pragma unroll
            for (int j = 0; j < 2; ++j) {
                acc[j] = fmaf((&xv[j].x)[u], w1, acc[j]);
                acc[j] = fmaf((&av[j].x)[u], w2, acc[j]);
            }
        }
    }

    float onorm[2];
    #pragma unroll
    for (int j = 0; j < 2; ++j) {
        float o = leaky_f(acc[j]);
        float ss = o * o;
        #pragma unroll
        for (int off = 32; off; off >>= 1) ss += __shfl_xor(ss, off);
        o = o / (sqrtf(ss) + 1e-6f);
        onorm[j] = o;
        int n = bs + wid * 2 + j;
        if (n < N) OUT[(size_t)n * 64 + lane] = o;
    }

    // --- re-stage Q1w into the dead sW buffer, then fused layer-1 dense ---
    __syncthreads();   // everyone done reading W0w
    {
        const float4* s = (const float4*)Qw; float4* d = (float4*)sW;
        #pragma unroll
        for (int i = 0; i < 4; ++i) d[i * 256 + tid] = s[i * 256 + tid];
    }
    #pragma unroll
    for (int j = 0; j < 2; ++j)
        sx[(wid * 2 + j) * 64 + lane] = onorm[j];   // wave-local
    __syncthreads();   // Q1w staged

    const float qb = Qb[lane];
    float acc1[2] = {qb, qb};
    #pragma unroll
    for (int c4 = 0; c4 < 16; ++c4) {
        float4 xv[2];
        #pragma unroll
        for (int j = 0; j < 2; ++j) xv[j] = sx4[(wid * 2 + j) * 16 + c4];
        #pragma unroll
        for (int u = 0; u < 4; ++u) {
            float qv = sW[(c4 * 4 + u) * 64 + lane];
            #pragma unroll
            for (int j = 0; j < 2; ++j)
                acc1[j] = fmaf((&xv[j].x)[u], qv, acc1[j]);
        }
    }
    #pragma unroll
    for (int j = 0; j < 2; ++j) {
        int n = bs + wid * 2 + j;
        if (n < N) H1out[(size_t)n * 64 + lane] = leaky_f(acc1[j]);
    }
}

// ---------------------------------------------------------------------------
// K3: layer-1 conv. w from wcache (coalesced), gather h1, combine W1,
// normalize, write out in-place (block reads only its own rows first).
// ---------------------------------------------------------------------------
__global__ __launch_bounds__(256, 4) void k_conv(
    const float* __restrict__ X,
    const float* __restrict__ Hbuf,
    const float* __restrict__ wcache,
    const int*  __restrict__ nbr,
    const float* __restrict__ Ww,
    const float* __restrict__ Wb,
    float* __restrict__ OUT,
    int N)
{
    __shared__ float sW[128 * 64];
    __shared__ float sx[8 * 64];
    __shared__ float sa[8 * 64];
    __shared__ int   snb[8 * KN];
    __shared__ float ssw[8 * KN];

    const int tid  = threadIdx.x;
    const int wid  = tid >> 6;
    const int lane = tid & 63;
    const int bs   = blockIdx.x * 8;

    const int e    = tid;
    const int slot = e >> 5;
    int ng = bs + slot; if (ng >= N) ng = N - 1;
    const int   id = nbr[(size_t)ng * KN + (e & 31)];
    const float w  = wcache[(size_t)ng * KN + (e & 31)];

    {
        const float4* s = (const float4*)Ww; float4* d = (float4*)sW;
        #pragma unroll
        for (int i = 0; i < 8; ++i) d[i * 256 + tid] = s[i * 256 + tid];
    }
    #pragma unroll
    for (int j = 0; j < 2; ++j) {
        int sl = wid * 2 + j;
        int n = bs + sl; if (n >= N) n = N - 1;
        if (lane < 16)
            ((float4*)sx)[sl * 16 + lane] = ((const float4*)X)[(size_t)n * 16 + lane];
    }
    snb[e] = id;
    ssw[e] = w;

    float sumw[2], ag0[2], ag1[2];
    #pragma unroll
    for (int j = 0; j < 2; ++j) {
        float s = 0.f;
        #pragma unroll
        for (int k = 0; k < KN; ++k) s += ssw[wid * 64 + j * 32 + k];
        sumw[j] = s; ag0[j] = 0.f; ag1[j] = 0.f;
    }
    #pragma unroll 8
    for (int k = 0; k < KN; k += 2) {
        #pragma unroll
        for (int j = 0; j < 2; ++j) {
            size_t i0 = (size_t)snb[wid * 64 + j * 32 + k];
            size_t i1 = (size_t)snb[wid * 64 + j * 32 + k + 1];
            ag0[j] = fmaf(ssw[wid * 64 + j * 32 + k],     Hbuf[i0 * 64 + lane], ag0[j]);
            ag1[j] = fmaf(ssw[wid * 64 + j * 32 + k + 1], Hbuf[i1 * 64 + lane], ag1[j]);
        }
    }
    #pragma unroll
    for (int j = 0; j < 2; ++j)
        sa[(wid * 2 + j) * 64 + lane] = (ag0[j] + ag1[j]) / (sumw[j] + 1e-6f);
    __syncthreads();

    const float4* sx4 = (const float4*)sx;
    const float4* sa4 = (const float4*)sa;
    const float wb = Wb[lane];
    float acc[2] = {wb, wb};
    #pragma unroll
    for (int c4 = 0; c4 < 16; ++c4) {
        float4 xv[2], av[2];
        #pragma unroll
        for (int j = 0; j < 2; ++j) {
            xv[j] = sx4[(wid * 2 + j) * 16 + c4];
            av[j] = sa4[(wid * 2 + j) * 16 + c4];
        }
        #pragma unroll
        for (int u = 0; u < 4; ++u) {
            int c = c4 * 4 + u;
            float w1 = sW[c * 64 + lane];
            float w2 = sW[(64 + c) * 64 + lane];
            #pragma unroll
            for (int j = 0; j < 2; ++j) {
                acc[j] = fmaf((&xv[j].x)[u], w1, acc[j]);
                acc[j] = fmaf((&av[j].x)[u], w2, acc[j]);
            }
        }
    }

    #pragma unroll
    for (int j = 0; j < 2; ++j) {
        float o = leaky_f(acc[j]);
        float ss = o * o;
        #pragma unroll
        for (int off = 32; off; off >>= 1) ss += __shfl_xor(ss, off);
        int n = bs + wid * 2 + j;
        if (n < N) OUT[(size_t)n * 64 + lane] = o / (sqrtf(ss) + 1e-6f);
    }
}

extern "C" void kernel_launch(void* const* d_in, const int* in_sizes, int n_in,
                              void* d_out, int out_size, void* d_ws, size_t ws_size,
                              hipStream_t stream)
{
    const float* emb  = (const float*)d_in[0];
    const float* wmat = (const float*)d_in[1];
    const int*   nbr  = (const int*)  d_in[2];
    const float* Q0w  = (const float*)d_in[3];
    const float* Q0b  = (const float*)d_in[4];
    const float* W0w  = (const float*)d_in[5];
    const float* W0b  = (const float*)d_in[6];
    const float* Q1w  = (const float*)d_in[7];
    const float* Q1b  = (const float*)d_in[8];
    const float* W1w  = (const float*)d_in[9];
    const float* W1b  = (const float*)d_in[10];
    float* out = (float*)d_out;

    const int N = in_sizes[2] / KN;              // 12000
    const size_t row_bytes = (size_t)N * 64 * sizeof(float);

    float* h0 = (float*)d_ws;
    float* h1 = h0 + (size_t)N * 64;
    float* wc = h1 + (size_t)N * 64;
    const size_t need = 2 * row_bytes + (size_t)N * KN * sizeof(float);
    float* wcache = (ws_size >= need) ? wc : nullptr;

    const int gridD = (N + 15) / 16;   // 750
    const int gridC = (N + 7) / 8;     // 1500

    k_dense<<<gridD, 256, 0, stream>>>(emb, Q0w, Q0b, h0, N);
    k_conv_fused<<<gridC, 256, 0, stream>>>(emb, h0, wmat, nbr, wcache,
                                            W0w, W0b, Q1w, Q1b, out, h1, N);
    if (wcache)
        k_conv<<<gridC, 256, 0, stream>>>(out, h1, wcache, nbr, W1w, W1b, out, N);
    else {
        // fallback (shouldn't happen: ws is large) — re-gather from wmat
        k_conv_fused<<<gridC, 256, 0, stream>>>(out, h1, wmat, nbr, nullptr,
                                                W1w, W1b, Q1w, Q1b, out, h0, N);
    }
}

// Round 7
// 73.132 us; speedup vs baseline: 9.1572x; 3.1095x over previous
//
#include <hip/hip_runtime.h>
#include <math.h>

#define ALPHA 0.3f
#define K_NBR 32

__device__ __forceinline__ float leaky_f(float x) { return x >= 0.f ? x : ALPHA * x; }

// Hout[n,h] = leaky( sum_c X[n,c] * Qw[c,h] + Qb[h] ),  X: N x 64, Qw: 64 x 64
__global__ __launch_bounds__(256) void k_dense64(const float* __restrict__ X,
                                                 const float* __restrict__ Qw,
                                                 const float* __restrict__ Qb,
                                                 float* __restrict__ Hout, int N)
{
    __shared__ float sQ[64 * 64];
    __shared__ float sX[4 * 64];
    const int tid  = threadIdx.x;
    const int wid  = tid >> 6;   // wave (node slot) 0..3
    const int lane = tid & 63;   // h
    const int nr   = blockIdx.x * 4 + wid;
    const int n    = nr < N ? nr : N - 1;
    const bool valid = nr < N;

    #pragma unroll
    for (int i = 0; i < 16; ++i)
        sQ[i * 256 + tid] = Qw[i * 256 + tid];
    sX[wid * 64 + lane] = X[(long long)n * 64 + lane];
    __syncthreads();

    float acc = Qb[lane];
    #pragma unroll
    for (int c = 0; c < 64; ++c)
        acc = fmaf(sX[wid * 64 + c], sQ[c * 64 + lane], acc);
    if (valid)
        Hout[(long long)n * 64 + lane] = leaky_f(acc);
}

// Per node n (one wave each, 4 nodes/block):
//   w_k   = weights[n, nbr[n,k]]            (mode 0: gather + cache; mode 1: read cache)
//   agg_h = sum_k w_k * Hbuf[nbr[n,k], h] / (sum_k w_k + 1e-6)
//   cat   = [X[n,:], agg]                    (128)
//   o_h   = leaky( sum_d cat[d] * Ww[d,h] + Wb[h] )
//   OUT[n,h] = o_h / (||o||_2 + 1e-6)
// FUSE: additionally H1out[n,h] = leaky( sum_c OUT[n,c]*Q1w[c,h] + Q1b[h] )
//   -- node-local; OUT[n,c] via __shfl, Q1w straight from L2 (16KB, hot).
// Safe in-place (OUT may alias X): wave reads X[n,:] before writing OUT[n,:].
template<bool FUSE>
__global__ __launch_bounds__(256) void k_conv(const float* __restrict__ X,
                                              const float* __restrict__ Hbuf,
                                              const float* __restrict__ Wmat, // N x N
                                              const int*  __restrict__ nbr,   // N x 32
                                              float* __restrict__ wcache,     // N x 32 or null
                                              const float* __restrict__ Ww,   // 128 x 64
                                              const float* __restrict__ Wb,   // 64
                                              const float* __restrict__ Q1w,  // 64 x 64 (FUSE)
                                              const float* __restrict__ Q1b,  // 64 (FUSE)
                                              float* __restrict__ OUT,
                                              float* __restrict__ H1out,      // (FUSE)
                                              int N, int mode)
{
    __shared__ float sW[128 * 64];  // 32 KB
    __shared__ float sw[4][32];
    __shared__ int   snb[4][32];
    __shared__ float sx[4][64];
    __shared__ float sa[4][64];

    const int tid  = threadIdx.x;
    const int wid  = tid >> 6;
    const int lane = tid & 63;
    const int nr   = blockIdx.x * 4 + wid;
    const int n    = nr < N ? nr : N - 1;
    const bool valid = nr < N;

    #pragma unroll
    for (int i = 0; i < 32; ++i)
        sW[i * 256 + tid] = Ww[i * 256 + tid];

    sx[wid][lane] = X[(long long)n * 64 + lane];
    if (lane < K_NBR) {
        int id = nbr[n * K_NBR + lane];
        snb[wid][lane] = id;
        float w;
        if (mode == 0) {
            w = Wmat[(long long)n * N + id];
            if (wcache && valid) wcache[n * K_NBR + lane] = w;
        } else {
            w = wcache[n * K_NBR + lane];
        }
        sw[wid][lane] = w;
    }
    __syncthreads();

    float sumw = 0.f;
    #pragma unroll
    for (int k = 0; k < K_NBR; ++k) sumw += sw[wid][k];

    float agg = 0.f;
    #pragma unroll 8
    for (int k = 0; k < K_NBR; ++k) {
        long long id = snb[wid][k];
        agg = fmaf(sw[wid][k], Hbuf[id * 64 + lane], agg);
    }
    agg = agg / (sumw + 1e-6f);
    sa[wid][lane] = agg;
    __syncthreads();

    float acc = Wb[lane];
    #pragma unroll
    for (int c = 0; c < 64; ++c)
        acc = fmaf(sx[wid][c], sW[c * 64 + lane], acc);
    #pragma unroll
    for (int c = 0; c < 64; ++c)
        acc = fmaf(sa[wid][c], sW[(64 + c) * 64 + lane], acc);

    float o = leaky_f(acc);
    float ss = o * o;
    #pragma unroll
    for (int off = 32; off; off >>= 1)
        ss += __shfl_xor(ss, off);
    const float on = o / (sqrtf(ss) + 1e-6f);
    if (valid)
        OUT[(long long)n * 64 + lane] = on;

    if (FUSE) {
        // h1 = leaky(out0 . Q1 + Q1b): out0[n,c] = __shfl(on, c); Q1w from L2.
        float acc1 = Q1b[lane];
        #pragma unroll 8
        for (int c = 0; c < 64; ++c)
            acc1 = fmaf(__shfl(on, c), Q1w[c * 64 + lane], acc1);
        if (valid)
            H1out[(long long)n * 64 + lane] = leaky_f(acc1);
    }
}

extern "C" void kernel_launch(void* const* d_in, const int* in_sizes, int n_in,
                              void* d_out, int out_size, void* d_ws, size_t ws_size,
                              hipStream_t stream)
{
    const float* emb  = (const float*)d_in[0];  // (1, N, 64)
    const float* wmat = (const float*)d_in[1];  // (N, N)
    const int*   nbr  = (const int*)  d_in[2];  // (N, 32) int32
    const float* Q0w  = (const float*)d_in[3];
    const float* Q0b  = (const float*)d_in[4];
    const float* W0w  = (const float*)d_in[5];
    const float* W0b  = (const float*)d_in[6];
    const float* Q1w  = (const float*)d_in[7];
    const float* Q1b  = (const float*)d_in[8];
    const float* W1w  = (const float*)d_in[9];
    const float* W1b  = (const float*)d_in[10];
    float* out = (float*)d_out;

    const int N = in_sizes[2] / K_NBR;          // 12000
    const size_t hbuf_bytes = (size_t)N * 64 * sizeof(float);
    const size_t wc_bytes   = (size_t)N * K_NBR * sizeof(float);

    float* h0 = (float*)d_ws;                              // h0
    float* h1 = (float*)((char*)d_ws + hbuf_bytes);        // h1 (disjoint)
    bool use_wc = ws_size >= 2 * hbuf_bytes + wc_bytes;
    float* wcache = use_wc ? (float*)((char*)d_ws + 2 * hbuf_bytes) : nullptr;

    const int grid = (N + 3) / 4;   // 3000

    // L0 dense: h0 = leaky(emb.Q0+b)
    k_dense64<<<grid, 256, 0, stream>>>(emb, Q0w, Q0b, h0, N);
    // L0 conv (+ fused L1 dense): emb,h0 -> out0(d_out), h1
    k_conv<true><<<grid, 256, 0, stream>>>(emb, h0, wmat, nbr, wcache,
                                           W0w, W0b, Q1w, Q1b, out, h1, N, 0);
    // L1 conv: out0,h1 -> out (in-place); weights from cache if available
    k_conv<false><<<grid, 256, 0, stream>>>(out, h1, wmat, nbr, wcache,
                                            W1w, W1b, nullptr, nullptr, out, nullptr,
                                            N, use_wc ? 1 : 0);
}

// Round 8
// 64.064 us; speedup vs baseline: 10.4534x; 1.1415x over previous
//
#include <hip/hip_runtime.h>
#include <math.h>

#define ALPHA 0.3f
#define KN 32

__device__ __forceinline__ float leaky_f(float x) { return x >= 0.f ? x : ALPHA * x; }

// ---------------------------------------------------------------------------
// K_A: for 16 nodes/block (4 waves x 4 iterations):
//   h0[n,h] = leaky( sum_c emb[n,c]*Q0w[c,h] + Q0b[h] )
//   wcache[n,k] = wmat[n, nbr[n,k]]   (issued FIRST: HBM-random latency
//                                      hides under the dense math)
// ---------------------------------------------------------------------------
__global__ __launch_bounds__(256) void k_dense_gather(
    const float* __restrict__ X,
    const float* __restrict__ Qw,
    const float* __restrict__ Qb,
    const float* __restrict__ wmat,
    const int*  __restrict__ nbr,
    float* __restrict__ wcache,      // may be null
    float* __restrict__ Hout,
    int N)
{
    __shared__ float sQ[64 * 64];
    __shared__ float sX[4][64];
    const int tid  = threadIdx.x;
    const int wid  = tid >> 6;
    const int lane = tid & 63;
    const int bs   = blockIdx.x * 16;

    // --- random gathers first: 512 (node,k) entries = 2 per thread ---
    int gid[2]; float gw[2];
    #pragma unroll
    for (int u = 0; u < 2; ++u) {
        int e = tid + u * 256;
        int n = bs + (e >> 5); if (n >= N) n = N - 1;
        gid[u] = nbr[(size_t)n * KN + (e & 31)];
    }
    #pragma unroll
    for (int u = 0; u < 2; ++u) {
        int e = tid + u * 256;
        int n = bs + (e >> 5); if (n >= N) n = N - 1;
        gw[u] = wmat[(size_t)n * (size_t)N + gid[u]];
    }

    // --- stage Q0 (float4, 4/thread) while gathers are in flight ---
    {
        const float4* s = (const float4*)Qw; float4* d = (float4*)sQ;
        #pragma unroll
        for (int i = 0; i < 4; ++i) d[i * 256 + tid] = s[i * 256 + tid];
    }
    __syncthreads();

    const float qb = Qb[lane];
    #pragma unroll
    for (int g = 0; g < 4; ++g) {
        int nr = bs + g * 4 + wid;
        int n  = nr < N ? nr : N - 1;
        sX[wid][lane] = X[(size_t)n * 64 + lane];   // wave-local slot
        float acc = qb;
        #pragma unroll
        for (int c = 0; c < 64; ++c)
            acc = fmaf(sX[wid][c], sQ[c * 64 + lane], acc);
        if (nr < N) Hout[(size_t)n * 64 + lane] = leaky_f(acc);
    }

    // --- persist gathered weights (coalesced) ---
    if (wcache) {
        #pragma unroll
        for (int u = 0; u < 2; ++u) {
            int e = tid + u * 256;
            if (bs + (e >> 5) < N) wcache[(size_t)bs * KN + e] = gw[u];
        }
    }
}

// ---------------------------------------------------------------------------
// K_B/K_C: conv layer (8 nodes/block = 4 waves x 2 groups).
//   w_k from wcache (mode 1) or wmat gather (mode 0 fallback)
//   agg = sum_k w_k*Hbuf[nbr,:] / (sum_k w_k + 1e-6)
//   o = leaky([x,agg].Ww + Wb);  OUT[n] = o/(||o||+1e-6)
//   FUSE: H1out[n] = leaky(OUT[n].Q1w + Q1b)   (node-local; Q1w from L1/L2)
// In-place safe (OUT may alias X): wave reads its own X row before writing.
// Group-1 inputs prefetched to registers during group-0 compute.
// ---------------------------------------------------------------------------
template<bool FUSE>
__global__ __launch_bounds__(256) void k_conv(
    const float* __restrict__ X,
    const float* __restrict__ Hbuf,
    const float* __restrict__ Wmat,
    const float* __restrict__ wcache,
    const int*  __restrict__ nbr,
    const float* __restrict__ Ww,    // 128 x 64
    const float* __restrict__ Wb,
    const float* __restrict__ Q1w,   // 64 x 64 (FUSE)
    const float* __restrict__ Q1b,   // 64     (FUSE)
    float* __restrict__ OUT,
    float* __restrict__ H1out,
    int N, int mode)
{
    __shared__ float sW[128 * 64];   // 32 KB
    __shared__ float sw[4][32];
    __shared__ int   snb[4][32];
    __shared__ float sx[4][64];
    __shared__ float sa[4][64];      // 35 KB total -> 4 blocks/CU

    const int tid  = threadIdx.x;
    const int wid  = tid >> 6;
    const int lane = tid & 63;
    const int bs   = blockIdx.x * 8;

    // --- group-0 loads first (overlap with W staging) ---
    int n0 = bs + wid; if (n0 >= N) n0 = N - 1;
    float x0 = X[(size_t)n0 * 64 + lane];
    int id0 = 0; float wv0 = 0.f;
    if (lane < KN) {
        id0 = nbr[(size_t)n0 * KN + lane];
        wv0 = (mode == 1) ? wcache[(size_t)n0 * KN + lane]
                          : Wmat[(size_t)n0 * (size_t)N + id0];
    }

    // --- stage Ww (float4, 8/thread) ---
    {
        const float4* s = (const float4*)Ww; float4* d = (float4*)sW;
        #pragma unroll
        for (int i = 0; i < 8; ++i) d[i * 256 + tid] = s[i * 256 + tid];
    }
    sx[wid][lane] = x0;
    if (lane < KN) { snb[wid][lane] = id0; sw[wid][lane] = wv0; }
    __syncthreads();   // sW ready (and g0 LDS visible within wave)

    const float wb = Wb[lane];
    const float qb = FUSE ? Q1b[lane] : 0.f;

    float x1 = 0.f; int id1 = 0; float wv1 = 0.f;   // group-1 prefetch regs

    #pragma unroll
    for (int g = 0; g < 2; ++g) {
        const int nr = bs + g * 4 + wid;

        if (g == 0) {
            // prefetch group 1 into registers; loads drain under g0 compute
            int n1 = bs + 4 + wid; if (n1 >= N) n1 = N - 1;
            x1 = X[(size_t)n1 * 64 + lane];
            if (lane < KN) {
                id1 = nbr[(size_t)n1 * KN + lane];
                wv1 = (mode == 1) ? wcache[(size_t)n1 * KN + lane]
                                  : Wmat[(size_t)n1 * (size_t)N + id1];
            }
        }

        // --- neighbor aggregation (wave-local LDS) ---
        float sumw = 0.f;
        #pragma unroll
        for (int k = 0; k < KN; ++k) sumw += sw[wid][k];

        float agg = 0.f;
        #pragma unroll 8
        for (int k = 0; k < KN; ++k) {
            size_t id = (size_t)snb[wid][k];
            agg = fmaf(sw[wid][k], Hbuf[id * 64 + lane], agg);
        }
        sa[wid][lane] = agg / (sumw + 1e-6f);

        // --- combine GEMV ---
        float acc = wb;
        #pragma unroll
        for (int c = 0; c < 64; ++c)
            acc = fmaf(sx[wid][c], sW[c * 64 + lane], acc);
        #pragma unroll
        for (int c = 0; c < 64; ++c)
            acc = fmaf(sa[wid][c], sW[(64 + c) * 64 + lane], acc);

        float o = leaky_f(acc);
        float ss = o * o;
        #pragma unroll
        for (int off = 32; off; off >>= 1) ss += __shfl_xor(ss, off);
        const float on = o / (sqrtf(ss) + 1e-6f);
        if (nr < N) OUT[(size_t)nr * 64 + lane] = on;

        if (FUSE) {
            float acc1 = qb;
            #pragma unroll 8
            for (int c = 0; c < 64; ++c)
                acc1 = fmaf(__shfl(on, c), Q1w[c * 64 + lane], acc1);
            if (nr < N) H1out[(size_t)nr * 64 + lane] = leaky_f(acc1);
        }

        if (g == 0) {
            // install group-1 inputs (wave-local slots; no block barrier)
            sx[wid][lane] = x1;
            if (lane < KN) { snb[wid][lane] = id1; sw[wid][lane] = wv1; }
        }
    }
}

extern "C" void kernel_launch(void* const* d_in, const int* in_sizes, int n_in,
                              void* d_out, int out_size, void* d_ws, size_t ws_size,
                              hipStream_t stream)
{
    const float* emb  = (const float*)d_in[0];  // (1, N, 64)
    const float* wmat = (const float*)d_in[1];  // (N, N)
    const int*   nbr  = (const int*)  d_in[2];  // (N, 32) int32
    const float* Q0w  = (const float*)d_in[3];
    const float* Q0b  = (const float*)d_in[4];
    const float* W0w  = (const float*)d_in[5];
    const float* W0b  = (const float*)d_in[6];
    const float* Q1w  = (const float*)d_in[7];
    const float* Q1b  = (const float*)d_in[8];
    const float* W1w  = (const float*)d_in[9];
    const float* W1b  = (const float*)d_in[10];
    float* out = (float*)d_out;

    const int N = in_sizes[2] / KN;             // 12000
    const size_t hbuf_bytes = (size_t)N * 64 * sizeof(float);
    const size_t wc_bytes   = (size_t)N * KN * sizeof(float);

    float* h0 = (float*)d_ws;
    float* h1 = (float*)((char*)d_ws + hbuf_bytes);
    bool use_wc = ws_size >= 2 * hbuf_bytes + wc_bytes;
    float* wcache = use_wc ? (float*)((char*)d_ws + 2 * hbuf_bytes) : nullptr;
    const int mode = use_wc ? 1 : 0;

    const int gridA = (N + 15) / 16;   // 750
    const int gridC = (N + 7) / 8;     // 1500

    // K_A: h0 + wcache (gather overlapped with dense)
    k_dense_gather<<<gridA, 256, 0, stream>>>(emb, Q0w, Q0b, wmat, nbr,
                                              wcache, h0, N);
    // K_B: layer-0 conv (+ fused layer-1 dense): emb,h0 -> out0, h1
    k_conv<true><<<gridC, 256, 0, stream>>>(emb, h0, wmat, wcache, nbr,
                                            W0w, W0b, Q1w, Q1b, out, h1, N, mode);
    // K_C: layer-1 conv (in-place on out)
    k_conv<false><<<gridC, 256, 0, stream>>>(out, h1, wmat, wcache, nbr,
                                             W1w, W1b, nullptr, nullptr,
                                             out, nullptr, N, mode);
}